// Round 11
// baseline (125.569 us; speedup 1.0000x reference)
//
#include <hip/hip_runtime.h>
#include <math.h>

// KPConv fused, round 11: R10 + LDS diet -> 5 blocks/CU (occupancy lever only).
//   wT 16->15 rows (lane15 A-frag clamps to row14; D row15 discarded anyway)
//   SWT 536->520, cind int->ushort. All math byte-identical to R10 (passed).
// Shapes: N=50000, M=50000, H=40, K=15, CIN=64, COUT=128.
typedef unsigned short ushort_t;
typedef __attribute__((ext_vector_type(8))) short bf16x8;   // 8 bf16 = 4 VGPRs
typedef __attribute__((ext_vector_type(4))) float f32x4;

constexpr int H    = 40;
constexpr int KKP  = 15;
constexpr int CIN  = 64;
constexpr int COUT = 128;
constexpr int QB   = 8;          // queries per block
constexpr int NP   = QB * H;     // 320 (q,h) pairs per block
constexpr int SWF  = 984;        // WF16 row stride (validated R8/R10 Phase C)
constexpr int SWT  = 520;        // wT row stride elems: 1040B, 16B-mult, bank step 4
constexpr float INV_KPE = 1.0f / 1.2f;

__device__ __forceinline__ ushort_t f2bf(float f) {   // fp32 -> bf16 RNE
    union { float f; unsigned u; } v; v.f = f;
    unsigned r = v.u + 0x7FFFu + ((v.u >> 16) & 1u);
    return (ushort_t)(r >> 16);
}
__device__ __forceinline__ unsigned pk2(ushort_t a, ushort_t b) {
    return (unsigned)a | ((unsigned)b << 16);
}

// ---- kernel 1: per-support-row feature sums (reduction order UNCHANGED) + bf16 x copy
__global__ __launch_bounds__(256) void prep_kernel(const float* __restrict__ x,
                                                   float* __restrict__ rowsum,
                                                   ushort_t* __restrict__ xb,
                                                   int M, int write_xb) {
    int row  = blockIdx.x * 4 + (threadIdx.x >> 6);
    int lane = threadIdx.x & 63;
    if (row >= M) return;
    float v = x[row * CIN + lane];   // CIN == 64 == wave width
    if (write_xb) xb[row * CIN + lane] = f2bf(v);
    #pragma unroll
    for (int off = 32; off > 0; off >>= 1) v += __shfl_down(v, off, 64);
    if (lane == 0) rowsum[row] = v;
}

// ---- kernel 2: W -> bf16 MFMA-fragment order (UNCHANGED, validated R2..R10) ---
__global__ __launch_bounds__(256) void wprep_kernel(const float* __restrict__ wmat,
                                                    ushort_t* __restrict__ wb) {
    int t = blockIdx.x * 256 + threadIdx.x;
    if (t >= 30 * 8 * 64) return;
    int lane = t & 63;
    int ot   = (t >> 6) & 7;
    int jt   = t >> 9;
    int o  = ot * 16 + (lane & 15);
    int kb = jt * 32 + (lane >> 4) * 8;
    unsigned pk[4];
    #pragma unroll
    for (int r = 0; r < 4; ++r) {
        unsigned lo = f2bf(wmat[(kb + 2 * r) * COUT + o]);
        unsigned hi = f2bf(wmat[(kb + 2 * r + 1) * COUT + o]);
        pk[r] = lo | (hi << 16);
    }
    *(uint4*)&wb[(size_t)t * 8] = make_uint4(pk[0], pk[1], pk[2], pk[3]);
}

// ---- kernel 3: fused KPConv ---------------------------------------------------
// LDS: wT 15600 + WF16 15488 + cind 1024 + qcnt 32 + cnt 32 = 32176 B -> 5 blk/CU
template<bool BF16X>
__global__ __launch_bounds__(256, 5) void kpconv_main(
    const float* __restrict__ q_pts, const float* __restrict__ s_pts,
    const int*   __restrict__ nbinds, const float* __restrict__ xf,
    const ushort_t* __restrict__ xb,  const float* __restrict__ kp,
    const ushort_t* __restrict__ wb,  const float* __restrict__ rowsum,
    float* __restrict__ out, int N, int M)
{
    __shared__ __align__(16) ushort_t wT[15 * SWT];   // w^T: [kp][q*64+slot] bf16
    __shared__ __align__(16) ushort_t WF16[QB * SWF]; // bf16 WF, [q][k*64+c]
    __shared__ __align__(16) ushort_t cind[QB * 64];  // [q][slot] -> support row (0-init)
    __shared__ int qcnt[QB];                          // active slots per q
    __shared__ int cnt[QB];                           // valid-neighbor count (normalizer)

    const int tid = threadIdx.x;
    const int q0  = blockIdx.x * QB;

    // zero wT (pad slots must be 0) and cind (pad slots -> row 0, finite x)
    for (int i = tid; i < 15 * SWT / 8; i += 256)      // 975 uint4
        ((uint4*)wT)[i] = make_uint4(0, 0, 0, 0);
    if (tid < QB * 64 / 8) ((uint4*)cind)[tid] = make_uint4(0, 0, 0, 0);
    if (tid < QB) { qcnt[tid] = 0; cnt[tid] = 0; }
    __syncthreads();

    // ---------------- Phase A: KP weights + validity + compaction --------------
    // (math byte-identical to R8/R10)
    for (int p = tid; p < NP; p += 256) {
        int q  = p / H;
        int h  = p - q * H;
        int gq = q0 + q;
        int ind = nbinds[gq * H + h];
        bool shadow = (ind >= M);
        float nx = 0.f, ny = 0.f, nz = 0.f;
        if (!shadow) {
            nx = s_pts[ind * 3 + 0] - q_pts[gq * 3 + 0];
            ny = s_pts[ind * 3 + 1] - q_pts[gq * 3 + 1];
            nz = s_pts[ind * 3 + 2] - q_pts[gq * 3 + 2];
            if (rowsum[ind] > 0.0f) atomicAdd(&cnt[q], 1);
        }
        float n2 = nx * nx + ny * ny + nz * nz;
        float w[KKP];
        float wmax = 0.f;
        #pragma unroll
        for (int k = 0; k < KKP; ++k) {
            float wv = 0.f;
            if (!shadow) {
                float kx = kp[k * 3 + 0], ky = kp[k * 3 + 1], kz = kp[k * 3 + 2];
                float k2 = kx * kx + ky * ky + kz * kz;
                float cross = nx * kx + ny * ky + nz * kz;
                float sq = fmaxf(n2 + k2 - 2.0f * cross, 0.0f);
                wv = fmaxf(1.0f - sqrtf(sq) * INV_KPE, 0.0f);
            }
            w[k] = wv;
            wmax = fmaxf(wmax, wv);
        }
        if (wmax > 0.f) {
            int slot = atomicAdd(&qcnt[q], 1);
            int col  = q * 64 + slot;
            cind[col] = (ushort_t)ind;
            #pragma unroll
            for (int k = 0; k < KKP; ++k)
                wT[k * SWT + col] = f2bf(w[k]);   // transposed store
        }
    }
    __syncthreads();

    // ---------------- Phase B: WF[q] via MFMA ----------------------------------
    // A-frag: lane holds wT[kp=min(lane&15,14)][q*64 + kg*8 + i] (ds_read_b128);
    //         lane15's D row (kp 15) is a discarded duplicate of row 14.
    // B-frag: lane holds x[slot=kg*8+i][chan=wid*16+l15]   (register gather)
    // D:      row=(lane>>4)*4+reg -> kp, col=lane&15 -> chan (validated layout)
    const int wid  = tid >> 6;
    const int lane = tid & 63;
    const int l15  = lane & 15;
    const int kg   = lane >> 4;
    const int chan = wid * 16 + l15;
    const int arow = min(l15, 14);

    ushort_t va[16], vbuf[16];
    #define LOADQ(qq, arr)                                                        \
        {                                                                         \
            const int cb_ = (qq) * 64;                                            \
            _Pragma("unroll")                                                     \
            for (int i = 0; i < 8; ++i) {                                         \
                int i0 = cind[cb_ + kg * 8 + i];                                  \
                int i1 = cind[cb_ + 32 + kg * 8 + i];                             \
                if (BF16X) {                                                      \
                    (arr)[i]     = xb[((unsigned)i0 << 6) + chan];                \
                    (arr)[8 + i] = xb[((unsigned)i1 << 6) + chan];                \
                } else {                                                          \
                    (arr)[i]     = f2bf(xf[((unsigned)i0 << 6) + chan]);          \
                    (arr)[8 + i] = f2bf(xf[((unsigned)i1 << 6) + chan]);          \
                }                                                                 \
            }                                                                     \
        }
    #define CONSUMEQ(qq, arr)                                                     \
        {                                                                         \
            union { uint4 u; bf16x8 b; } b0_, b1_;                                \
            b0_.u = make_uint4(pk2((arr)[0], (arr)[1]),  pk2((arr)[2], (arr)[3]), \
                               pk2((arr)[4], (arr)[5]),  pk2((arr)[6], (arr)[7]));\
            b1_.u = make_uint4(pk2((arr)[8], (arr)[9]),  pk2((arr)[10],(arr)[11]),\
                               pk2((arr)[12],(arr)[13]), pk2((arr)[14],(arr)[15]));\
            bf16x8 a0_ = *(const bf16x8*)&wT[arow * SWT + (qq) * 64 + kg * 8];    \
            bf16x8 a1_ = *(const bf16x8*)&wT[arow * SWT + (qq) * 64 + 32 + kg * 8];\
            f32x4 acc_ = {0.f, 0.f, 0.f, 0.f};                                    \
            acc_ = __builtin_amdgcn_mfma_f32_16x16x32_bf16(a0_, b0_.b, acc_, 0,0,0);\
            acc_ = __builtin_amdgcn_mfma_f32_16x16x32_bf16(a1_, b1_.b, acc_, 0,0,0);\
            _Pragma("unroll")                                                     \
            for (int reg = 0; reg < 4; ++reg) {                                   \
                int kpr = kg * 4 + reg;                                           \
                if (kpr < KKP)                                                    \
                    WF16[(qq) * SWF + kpr * 64 + chan] = f2bf(acc_[reg]);         \
            }                                                                     \
        }

    LOADQ(0, va);
    #pragma unroll
    for (int q = 0; q < QB; q += 2) {
        if (q + 1 < QB) LOADQ(q + 1, vbuf);
        CONSUMEQ(q, va);
        if (q + 2 < QB) LOADQ(q + 2, va);
        if (q + 1 < QB) CONSUMEQ(q + 1, vbuf);
    }
    #undef LOADQ
    #undef CONSUMEQ
    __syncthreads();

    // ---------------- Phase C: out[q][o] via MFMA, 6-deep wb prefetch (R8) -----
    {
        const int qrow = lane & 7;
        const int ot0  = wid * 2;
        f32x4 c0 = {0.f,0.f,0.f,0.f}, c1 = {0.f,0.f,0.f,0.f};
        const ushort_t* wfrow = &WF16[qrow * SWF + kg * 8];
        const ushort_t* bbase = wb + ((size_t)(ot0 * 64 + lane)) * 8;

        bf16x8 rb0[6], rb1[6];
        #pragma unroll
        for (int i = 0; i < 6; ++i) {        // preload jt = 0..5
            rb0[i] = *(const bf16x8*)&bbase[(size_t)i * 4096];
            rb1[i] = *(const bf16x8*)&bbase[(size_t)i * 4096 + 512];
        }
        for (int m = 0; m < 5; ++m) {        // 5 x 6 = 30 jt steps
            #pragma unroll
            for (int u = 0; u < 6; ++u) {
                int jt = m * 6 + u;
                bf16x8 a = *(const bf16x8*)&wfrow[jt * 32];
                c0 = __builtin_amdgcn_mfma_f32_16x16x32_bf16(a, rb0[u], c0, 0, 0, 0);
                c1 = __builtin_amdgcn_mfma_f32_16x16x32_bf16(a, rb1[u], c1, 0, 0, 0);
                if (m < 4) {                 // prefetch jt+6 into freed slot
                    rb0[u] = *(const bf16x8*)&bbase[(size_t)(jt + 6) * 4096];
                    rb1[u] = *(const bf16x8*)&bbase[(size_t)(jt + 6) * 4096 + 512];
                }
            }
        }

        // C/D layout: col = lane&15, row = (lane>>4)*4 + reg. Rows 0..7 = queries.
        if (lane < 32) {
            int col = ot0 * 16 + (lane & 15);
            #pragma unroll
            for (int reg = 0; reg < 4; ++reg) {
                int row = (lane >> 4) * 4 + reg;
                float inv = 1.0f / (float)max(cnt[row], 1);
                int gq = q0 + row;
                if (gq < N) {
                    out[(size_t)gq * COUT + col]      = c0[reg] * inv;
                    out[(size_t)gq * COUT + col + 16] = c1[reg] * inv;
                }
            }
        }
    }
}

extern "C" void kernel_launch(void* const* d_in, const int* in_sizes, int n_in,
                              void* d_out, int out_size, void* d_ws, size_t ws_size,
                              hipStream_t stream) {
    const float* q_pts  = (const float*)d_in[0];
    const float* s_pts  = (const float*)d_in[1];
    const int*   nbinds = (const int*)d_in[2];
    const float* x      = (const float*)d_in[3];
    const float* kp     = (const float*)d_in[4];
    const float* wmat   = (const float*)d_in[5];
    float* out = (float*)d_out;
    int N = in_sizes[0] / 3;
    int M = in_sizes[1] / 3;

    // workspace carve: rowsum (M f32) | wb (245760 B) | xb (M*64 bf16)
    size_t    off_wb = ((size_t)M * 4 + 255) & ~(size_t)255;
    size_t    off_xb = (off_wb + 245760 + 255) & ~(size_t)255;
    size_t    need   = off_xb + (size_t)M * CIN * 2;
    float*    rowsum = (float*)d_ws;
    ushort_t* wb     = (ushort_t*)((char*)d_ws + off_wb);
    ushort_t* xb     = (ushort_t*)((char*)d_ws + off_xb);
    bool use_bf16x = (ws_size >= need) && (M < 65536);   // cind is ushort

    prep_kernel<<<(M + 3) / 4, 256, 0, stream>>>(x, rowsum, xb, M, use_bf16x ? 1 : 0);
    wprep_kernel<<<60, 256, 0, stream>>>(wmat, wb);
    int mb = (N + QB - 1) / QB;
    if (use_bf16x)
        kpconv_main<true><<<mb, 256, 0, stream>>>(q_pts, s_pts, nbinds, x, xb, kp,
                                                  wb, rowsum, out, N, M);
    else
        kpconv_main<false><<<mb, 256, 0, stream>>>(q_pts, s_pts, nbinds, x, xb, kp,
                                                   wb, rowsum, out, N, M);
}

// Round 12
// 111.416 us; speedup vs baseline: 1.1270x; 1.1270x over previous
//
#include <hip/hip_runtime.h>
#include <math.h>

// KPConv fused, round 12: QB=16, 512-thread blocks — Phase C D-tile fully used
// (16 real query rows; R11 wasted rows 8..15). All fragment layouts identical.
// Shapes: N=50000, M=50000, H=40, K=15, CIN=64, COUT=128.
typedef unsigned short ushort_t;
typedef __attribute__((ext_vector_type(8))) short bf16x8;   // 8 bf16 = 4 VGPRs
typedef __attribute__((ext_vector_type(4))) float f32x4;

constexpr int H    = 40;
constexpr int KKP  = 15;
constexpr int CIN  = 64;
constexpr int COUT = 128;
constexpr int QB   = 16;         // queries per block
constexpr int NT   = 512;        // threads per block (8 waves)
constexpr int NP   = QB * H;     // 640 (q,h) pairs per block
constexpr int SWF  = 968;        // WF16 row stride: 1936 B, bank step 4 -> 2-way free
constexpr int SWT  = 1032;       // wT row stride: 16*64 + 8 pad; 2064 B, step 4
constexpr float INV_KPE = 1.0f / 1.2f;

__device__ __forceinline__ ushort_t f2bf(float f) {   // fp32 -> bf16 RNE
    union { float f; unsigned u; } v; v.f = f;
    unsigned r = v.u + 0x7FFFu + ((v.u >> 16) & 1u);
    return (ushort_t)(r >> 16);
}
__device__ __forceinline__ unsigned pk2(ushort_t a, ushort_t b) {
    return (unsigned)a | ((unsigned)b << 16);
}

// ---- kernel 1: per-support-row feature sums (reduction order UNCHANGED) + bf16 x copy
__global__ __launch_bounds__(256) void prep_kernel(const float* __restrict__ x,
                                                   float* __restrict__ rowsum,
                                                   ushort_t* __restrict__ xb,
                                                   int M, int write_xb) {
    int row  = blockIdx.x * 4 + (threadIdx.x >> 6);
    int lane = threadIdx.x & 63;
    if (row >= M) return;
    float v = x[row * CIN + lane];   // CIN == 64 == wave width
    if (write_xb) xb[row * CIN + lane] = f2bf(v);
    #pragma unroll
    for (int off = 32; off > 0; off >>= 1) v += __shfl_down(v, off, 64);
    if (lane == 0) rowsum[row] = v;
}

// ---- kernel 2: W -> bf16 MFMA-fragment order (UNCHANGED, validated R2..R11) ---
__global__ __launch_bounds__(256) void wprep_kernel(const float* __restrict__ wmat,
                                                    ushort_t* __restrict__ wb) {
    int t = blockIdx.x * 256 + threadIdx.x;
    if (t >= 30 * 8 * 64) return;
    int lane = t & 63;
    int ot   = (t >> 6) & 7;
    int jt   = t >> 9;
    int o  = ot * 16 + (lane & 15);
    int kb = jt * 32 + (lane >> 4) * 8;
    unsigned pk[4];
    #pragma unroll
    for (int r = 0; r < 4; ++r) {
        unsigned lo = f2bf(wmat[(kb + 2 * r) * COUT + o]);
        unsigned hi = f2bf(wmat[(kb + 2 * r + 1) * COUT + o]);
        pk[r] = lo | (hi << 16);
    }
    *(uint4*)&wb[(size_t)t * 8] = make_uint4(pk[0], pk[1], pk[2], pk[3]);
}

// ---- kernel 3: fused KPConv ---------------------------------------------------
// LDS: wT 30960 + WF16 30976 + cind 2048 + qcnt 64 + cnt 64 = 64112 B -> 2 blk/CU
template<bool BF16X>
__global__ __launch_bounds__(NT, 4) void kpconv_main(
    const float* __restrict__ q_pts, const float* __restrict__ s_pts,
    const int*   __restrict__ nbinds, const float* __restrict__ xf,
    const ushort_t* __restrict__ xb,  const float* __restrict__ kp,
    const ushort_t* __restrict__ wb,  const float* __restrict__ rowsum,
    float* __restrict__ out, int N, int M)
{
    __shared__ __align__(16) ushort_t wT[15 * SWT];   // w^T: [kp][q*64+slot] bf16
    __shared__ __align__(16) ushort_t WF16[QB * SWF]; // bf16 WF, [q][k*64+c]
    __shared__ __align__(16) ushort_t cind[QB * 64];  // [q][slot] -> support row
    __shared__ int qcnt[QB];                          // active slots per q
    __shared__ int cnt[QB];                           // valid-neighbor count

    const int tid = threadIdx.x;
    const int q0  = blockIdx.x * QB;

    // zero wT (pad slots must be 0) and cind (pad slots -> row 0, finite x)
    for (int i = tid; i < 15 * SWT / 8; i += NT)      // 1935 uint4
        ((uint4*)wT)[i] = make_uint4(0, 0, 0, 0);
    if (tid < QB * 64 / 8) ((uint4*)cind)[tid] = make_uint4(0, 0, 0, 0);
    if (tid < QB) { qcnt[tid] = 0; cnt[tid] = 0; }
    __syncthreads();

    // ---------------- Phase A: KP weights + validity + compaction --------------
    // (math byte-identical to R8/R10/R11)
    for (int p = tid; p < NP; p += NT) {
        int q  = p / H;
        int h  = p - q * H;
        int gq = q0 + q;
        int ind = nbinds[gq * H + h];
        bool shadow = (ind >= M);
        float nx = 0.f, ny = 0.f, nz = 0.f;
        if (!shadow) {
            nx = s_pts[ind * 3 + 0] - q_pts[gq * 3 + 0];
            ny = s_pts[ind * 3 + 1] - q_pts[gq * 3 + 1];
            nz = s_pts[ind * 3 + 2] - q_pts[gq * 3 + 2];
            if (rowsum[ind] > 0.0f) atomicAdd(&cnt[q], 1);
        }
        float n2 = nx * nx + ny * ny + nz * nz;
        float w[KKP];
        float wmax = 0.f;
        #pragma unroll
        for (int k = 0; k < KKP; ++k) {
            float wv = 0.f;
            if (!shadow) {
                float kx = kp[k * 3 + 0], ky = kp[k * 3 + 1], kz = kp[k * 3 + 2];
                float k2 = kx * kx + ky * ky + kz * kz;
                float cross = nx * kx + ny * ky + nz * kz;
                float sq = fmaxf(n2 + k2 - 2.0f * cross, 0.0f);
                wv = fmaxf(1.0f - sqrtf(sq) * INV_KPE, 0.0f);
            }
            w[k] = wv;
            wmax = fmaxf(wmax, wv);
        }
        if (wmax > 0.f) {
            int slot = atomicAdd(&qcnt[q], 1);
            int col  = q * 64 + slot;
            cind[col] = (ushort_t)ind;
            #pragma unroll
            for (int k = 0; k < KKP; ++k)
                wT[k * SWT + col] = f2bf(w[k]);   // transposed store
        }
    }
    __syncthreads();

    // ---------------- Phase B: WF[q] via MFMA ----------------------------------
    // wave (qh = wid>>2) handles q in [qh*8, qh*8+8); (cg = wid&3) -> 16 chans.
    // A-frag: wT[min(l15,14)][q*64 + kg*8 + i] (ds_read_b128; D row15 discarded)
    // B-frag: x[slot=kg*8+i][chan] register gather; D: row->kp, col->chan.
    const int wid  = tid >> 6;
    const int lane = tid & 63;
    const int l15  = lane & 15;
    const int kg   = lane >> 4;
    const int cg   = wid & 3;
    const int qh   = wid >> 2;
    const int chan = cg * 16 + l15;
    const int arow = min(l15, 14);

    ushort_t va[16], vbuf[16];
    #define LOADQ(qq, arr)                                                        \
        {                                                                         \
            const int cb_ = (qq) * 64;                                            \
            _Pragma("unroll")                                                     \
            for (int i = 0; i < 8; ++i) {                                         \
                int i0 = cind[cb_ + kg * 8 + i];                                  \
                int i1 = cind[cb_ + 32 + kg * 8 + i];                             \
                if (BF16X) {                                                      \
                    (arr)[i]     = xb[((unsigned)i0 << 6) + chan];                \
                    (arr)[8 + i] = xb[((unsigned)i1 << 6) + chan];                \
                } else {                                                          \
                    (arr)[i]     = f2bf(xf[((unsigned)i0 << 6) + chan]);          \
                    (arr)[8 + i] = f2bf(xf[((unsigned)i1 << 6) + chan]);          \
                }                                                                 \
            }                                                                     \
        }
    #define CONSUMEQ(qq, arr)                                                     \
        {                                                                         \
            union { uint4 u; bf16x8 b; } b0_, b1_;                                \
            b0_.u = make_uint4(pk2((arr)[0], (arr)[1]),  pk2((arr)[2], (arr)[3]), \
                               pk2((arr)[4], (arr)[5]),  pk2((arr)[6], (arr)[7]));\
            b1_.u = make_uint4(pk2((arr)[8], (arr)[9]),  pk2((arr)[10],(arr)[11]),\
                               pk2((arr)[12],(arr)[13]), pk2((arr)[14],(arr)[15]));\
            bf16x8 a0_ = *(const bf16x8*)&wT[arow * SWT + (qq) * 64 + kg * 8];    \
            bf16x8 a1_ = *(const bf16x8*)&wT[arow * SWT + (qq) * 64 + 32 + kg * 8];\
            f32x4 acc_ = {0.f, 0.f, 0.f, 0.f};                                    \
            acc_ = __builtin_amdgcn_mfma_f32_16x16x32_bf16(a0_, b0_.b, acc_, 0,0,0);\
            acc_ = __builtin_amdgcn_mfma_f32_16x16x32_bf16(a1_, b1_.b, acc_, 0,0,0);\
            _Pragma("unroll")                                                     \
            for (int reg = 0; reg < 4; ++reg) {                                   \
                int kpr = kg * 4 + reg;                                           \
                if (kpr < KKP)                                                    \
                    WF16[(qq) * SWF + kpr * 64 + chan] = f2bf(acc_[reg]);         \
            }                                                                     \
        }

    {
        const int qb0 = qh * 8;
        LOADQ(qb0 + 0, va);
        #pragma unroll
        for (int iq = 0; iq < 8; iq += 2) {
            if (iq + 1 < 8) LOADQ(qb0 + iq + 1, vbuf);
            CONSUMEQ(qb0 + iq, va);
            if (iq + 2 < 8) LOADQ(qb0 + iq + 2, va);
            if (iq + 1 < 8) CONSUMEQ(qb0 + iq + 1, vbuf);
        }
    }
    #undef LOADQ
    #undef CONSUMEQ
    __syncthreads();

    // ---------------- Phase C: out[q][o] via MFMA, 6-deep wb prefetch ----------
    // wave owns output tile ot = wid (16 cols); all 16 D rows are real queries.
    {
        const int ot = wid;
        f32x4 c0 = {0.f, 0.f, 0.f, 0.f};
        const ushort_t* wfrow = &WF16[l15 * SWF + kg * 8];
        const ushort_t* bbase = wb + ((size_t)(ot * 64 + lane)) * 8;

        bf16x8 rb0[6];
        #pragma unroll
        for (int i = 0; i < 6; ++i)          // preload jt = 0..5
            rb0[i] = *(const bf16x8*)&bbase[(size_t)i * 4096];
        for (int m = 0; m < 5; ++m) {        // 5 x 6 = 30 jt steps
            #pragma unroll
            for (int u = 0; u < 6; ++u) {
                int jt = m * 6 + u;
                bf16x8 a = *(const bf16x8*)&wfrow[jt * 32];
                c0 = __builtin_amdgcn_mfma_f32_16x16x32_bf16(a, rb0[u], c0, 0, 0, 0);
                if (m < 4)                   // prefetch jt+6 into freed slot
                    rb0[u] = *(const bf16x8*)&bbase[(size_t)(jt + 6) * 4096];
            }
        }

        // C/D layout: col = lane&15, row = (lane>>4)*4 + reg. Rows 0..15 = queries.
        int col = ot * 16 + l15;
        #pragma unroll
        for (int reg = 0; reg < 4; ++reg) {
            int row = kg * 4 + reg;
            float inv = 1.0f / (float)max(cnt[row], 1);
            int gq = q0 + row;
            if (gq < N)
                out[(size_t)gq * COUT + col] = c0[reg] * inv;
        }
    }
}

extern "C" void kernel_launch(void* const* d_in, const int* in_sizes, int n_in,
                              void* d_out, int out_size, void* d_ws, size_t ws_size,
                              hipStream_t stream) {
    const float* q_pts  = (const float*)d_in[0];
    const float* s_pts  = (const float*)d_in[1];
    const int*   nbinds = (const int*)d_in[2];
    const float* x      = (const float*)d_in[3];
    const float* kp     = (const float*)d_in[4];
    const float* wmat   = (const float*)d_in[5];
    float* out = (float*)d_out;
    int N = in_sizes[0] / 3;
    int M = in_sizes[1] / 3;

    // workspace carve: rowsum (M f32) | wb (245760 B) | xb (M*64 bf16)
    size_t    off_wb = ((size_t)M * 4 + 255) & ~(size_t)255;
    size_t    off_xb = (off_wb + 245760 + 255) & ~(size_t)255;
    size_t    need   = off_xb + (size_t)M * CIN * 2;
    float*    rowsum = (float*)d_ws;
    ushort_t* wb     = (ushort_t*)((char*)d_ws + off_wb);
    ushort_t* xb     = (ushort_t*)((char*)d_ws + off_xb);
    bool use_bf16x = (ws_size >= need) && (M < 65536);   // cind is ushort

    prep_kernel<<<(M + 3) / 4, 256, 0, stream>>>(x, rowsum, xb, M, use_bf16x ? 1 : 0);
    wprep_kernel<<<60, 256, 0, stream>>>(wmat, wb);
    int mb = (N + QB - 1) / QB;
    if (use_bf16x)
        kpconv_main<true><<<mb, NT, 0, stream>>>(q_pts, s_pts, nbinds, x, xb, kp,
                                                 wb, rowsum, out, N, M);
    else
        kpconv_main<false><<<mb, NT, 0, stream>>>(q_pts, s_pts, nbinds, x, xb, kp,
                                                  wb, rowsum, out, N, M);
}

// Round 13
// 106.861 us; speedup vs baseline: 1.1751x; 1.0426x over previous
//
#include <hip/hip_runtime.h>
#include <math.h>

// KPConv fused, round 13: R12 + nc-adaptive Phase B (K16/K32/2xK32 tiers).
// Exploits sparsity: typical active-slot count ~4-10 of 64 padded slots.
// Shapes: N=50000, M=50000, H=40, K=15, CIN=64, COUT=128.
typedef unsigned short ushort_t;
typedef __attribute__((ext_vector_type(4))) short bf16x4;   // 4 bf16 = 2 VGPRs
typedef __attribute__((ext_vector_type(8))) short bf16x8;   // 8 bf16 = 4 VGPRs
typedef __attribute__((ext_vector_type(4))) float f32x4;

constexpr int H    = 40;
constexpr int KKP  = 15;
constexpr int CIN  = 64;
constexpr int COUT = 128;
constexpr int QB   = 16;         // queries per block
constexpr int NT   = 512;        // threads per block (8 waves)
constexpr int NP   = QB * H;     // 640 (q,h) pairs per block
constexpr int SWF  = 968;        // WF16 row stride: 1936 B, bank step 4 -> 2-way free
constexpr int SWT  = 1032;       // wT row stride: 2064 B, bank step 4
constexpr float INV_KPE = 1.0f / 1.2f;

#if __has_builtin(__builtin_amdgcn_mfma_f32_16x16x16_bf16)
#define MFMA_K16(a,b,c) __builtin_amdgcn_mfma_f32_16x16x16_bf16(a,b,c,0,0,0)
#else
#define MFMA_K16(a,b,c) __builtin_amdgcn_mfma_f32_16x16x16bf16_1k(a,b,c,0,0,0)
#endif

__device__ __forceinline__ ushort_t f2bf(float f) {   // fp32 -> bf16 RNE
    union { float f; unsigned u; } v; v.f = f;
    unsigned r = v.u + 0x7FFFu + ((v.u >> 16) & 1u);
    return (ushort_t)(r >> 16);
}
__device__ __forceinline__ unsigned pk2(ushort_t a, ushort_t b) {
    return (unsigned)a | ((unsigned)b << 16);
}

// ---- kernel 1: per-support-row feature sums (reduction order UNCHANGED) + bf16 x copy
__global__ __launch_bounds__(256) void prep_kernel(const float* __restrict__ x,
                                                   float* __restrict__ rowsum,
                                                   ushort_t* __restrict__ xb,
                                                   int M, int write_xb) {
    int row  = blockIdx.x * 4 + (threadIdx.x >> 6);
    int lane = threadIdx.x & 63;
    if (row >= M) return;
    float v = x[row * CIN + lane];   // CIN == 64 == wave width
    if (write_xb) xb[row * CIN + lane] = f2bf(v);
    #pragma unroll
    for (int off = 32; off > 0; off >>= 1) v += __shfl_down(v, off, 64);
    if (lane == 0) rowsum[row] = v;
}

// ---- kernel 2: W -> bf16 MFMA-fragment order (UNCHANGED, validated R2..R12) ---
__global__ __launch_bounds__(256) void wprep_kernel(const float* __restrict__ wmat,
                                                    ushort_t* __restrict__ wb) {
    int t = blockIdx.x * 256 + threadIdx.x;
    if (t >= 30 * 8 * 64) return;
    int lane = t & 63;
    int ot   = (t >> 6) & 7;
    int jt   = t >> 9;
    int o  = ot * 16 + (lane & 15);
    int kb = jt * 32 + (lane >> 4) * 8;
    unsigned pk[4];
    #pragma unroll
    for (int r = 0; r < 4; ++r) {
        unsigned lo = f2bf(wmat[(kb + 2 * r) * COUT + o]);
        unsigned hi = f2bf(wmat[(kb + 2 * r + 1) * COUT + o]);
        pk[r] = lo | (hi << 16);
    }
    *(uint4*)&wb[(size_t)t * 8] = make_uint4(pk[0], pk[1], pk[2], pk[3]);
}

// ---- kernel 3: fused KPConv ---------------------------------------------------
// LDS: wT 30960 + WF16 30976 + cind 2048 + qcnt 64 + cnt 64 = 64112 B -> 2 blk/CU
template<bool BF16X>
__global__ __launch_bounds__(NT, 4) void kpconv_main(
    const float* __restrict__ q_pts, const float* __restrict__ s_pts,
    const int*   __restrict__ nbinds, const float* __restrict__ xf,
    const ushort_t* __restrict__ xb,  const float* __restrict__ kp,
    const ushort_t* __restrict__ wb,  const float* __restrict__ rowsum,
    float* __restrict__ out, int N, int M)
{
    __shared__ __align__(16) ushort_t wT[15 * SWT];   // w^T: [kp][q*64+slot] bf16
    __shared__ __align__(16) ushort_t WF16[QB * SWF]; // bf16 WF, [q][k*64+c]
    __shared__ __align__(16) ushort_t cind[QB * 64];  // [q][slot] -> support row
    __shared__ int qcnt[QB];                          // active slots per q
    __shared__ int cnt[QB];                           // valid-neighbor count

    const int tid = threadIdx.x;
    const int q0  = blockIdx.x * QB;

    // zero wT (pad slots must be 0) and cind (pad slots -> row 0, finite x)
    for (int i = tid; i < 15 * SWT / 8; i += NT)      // 1935 uint4
        ((uint4*)wT)[i] = make_uint4(0, 0, 0, 0);
    if (tid < QB * 64 / 8) ((uint4*)cind)[tid] = make_uint4(0, 0, 0, 0);
    if (tid < QB) { qcnt[tid] = 0; cnt[tid] = 0; }
    __syncthreads();

    // ---------------- Phase A: KP weights + validity + compaction --------------
    // (math byte-identical to R8/R10/R11/R12)
    for (int p = tid; p < NP; p += NT) {
        int q  = p / H;
        int h  = p - q * H;
        int gq = q0 + q;
        int ind = nbinds[gq * H + h];
        bool shadow = (ind >= M);
        float nx = 0.f, ny = 0.f, nz = 0.f;
        if (!shadow) {
            nx = s_pts[ind * 3 + 0] - q_pts[gq * 3 + 0];
            ny = s_pts[ind * 3 + 1] - q_pts[gq * 3 + 1];
            nz = s_pts[ind * 3 + 2] - q_pts[gq * 3 + 2];
            if (rowsum[ind] > 0.0f) atomicAdd(&cnt[q], 1);
        }
        float n2 = nx * nx + ny * ny + nz * nz;
        float w[KKP];
        float wmax = 0.f;
        #pragma unroll
        for (int k = 0; k < KKP; ++k) {
            float wv = 0.f;
            if (!shadow) {
                float kx = kp[k * 3 + 0], ky = kp[k * 3 + 1], kz = kp[k * 3 + 2];
                float k2 = kx * kx + ky * ky + kz * kz;
                float cross = nx * kx + ny * ky + nz * kz;
                float sq = fmaxf(n2 + k2 - 2.0f * cross, 0.0f);
                wv = fmaxf(1.0f - sqrtf(sq) * INV_KPE, 0.0f);
            }
            w[k] = wv;
            wmax = fmaxf(wmax, wv);
        }
        if (wmax > 0.f) {
            int slot = atomicAdd(&qcnt[q], 1);
            int col  = q * 64 + slot;
            cind[col] = (ushort_t)ind;
            #pragma unroll
            for (int k = 0; k < KKP; ++k)
                wT[k * SWT + col] = f2bf(w[k]);   // transposed store
        }
    }
    __syncthreads();

    // ---------------- Phase B: WF[q] via MFMA, nc-adaptive tiers ----------------
    // wave (qh = wid>>2) handles q in [qh*8, qh*8+8); (cg = wid&3) -> 16 chans.
    // A-frag: wT[min(l15,14)][q*64 + kg*G + i]; B-frag: register gather; same
    // assumed k-map on both sides (permutation-cancelling, validated R10-12).
    const int wid  = tid >> 6;
    const int lane = tid & 63;
    const int l15  = lane & 15;
    const int kg   = lane >> 4;
    const int cg   = wid & 3;
    const int qh   = wid >> 2;
    const int chan = cg * 16 + l15;
    const int arow = min(l15, 14);

    ushort_t va[16], vbuf[16];
    #define LOADQ_N(qq, arr, NL)                                                  \
        {                                                                         \
            const int cb_ = (qq) * 64;                                            \
            _Pragma("unroll")                                                     \
            for (int i = 0; i < (NL); ++i) {                                      \
                int i0 = cind[cb_ + kg * (NL) + i];                               \
                if (BF16X) (arr)[i] = xb[((unsigned)i0 << 6) + chan];             \
                else       (arr)[i] = f2bf(xf[((unsigned)i0 << 6) + chan]);       \
            }                                                                     \
        }
    #define STORE_D(qq, acc_)                                                     \
        {                                                                         \
            _Pragma("unroll")                                                     \
            for (int reg = 0; reg < 4; ++reg) {                                   \
                int kpr = kg * 4 + reg;                                           \
                if (kpr < KKP)                                                    \
                    WF16[(qq) * SWF + kpr * 64 + chan] = f2bf(acc_[reg]);         \
            }                                                                     \
        }
    #define CONSUME4(qq, arr)                                                     \
        {                                                                         \
            union { uint2 u; bf16x4 b; } b_;                                      \
            b_.u = make_uint2(pk2((arr)[0], (arr)[1]), pk2((arr)[2], (arr)[3]));  \
            bf16x4 a_ = *(const bf16x4*)&wT[arow * SWT + (qq) * 64 + kg * 4];     \
            f32x4 acc_ = {0.f, 0.f, 0.f, 0.f};                                    \
            acc_ = MFMA_K16(a_, b_.b, acc_);                                      \
            STORE_D(qq, acc_)                                                     \
        }
    #define CONSUME8(qq, arr)                                                     \
        {                                                                         \
            union { uint4 u; bf16x8 b; } b_;                                      \
            b_.u = make_uint4(pk2((arr)[0], (arr)[1]), pk2((arr)[2], (arr)[3]),   \
                              pk2((arr)[4], (arr)[5]), pk2((arr)[6], (arr)[7]));  \
            bf16x8 a_ = *(const bf16x8*)&wT[arow * SWT + (qq) * 64 + kg * 8];     \
            f32x4 acc_ = {0.f, 0.f, 0.f, 0.f};                                    \
            acc_ = __builtin_amdgcn_mfma_f32_16x16x32_bf16(a_, b_.b, acc_, 0,0,0);\
            STORE_D(qq, acc_)                                                     \
        }
    #define LOADQ16(qq, arr)                                                      \
        {                                                                         \
            const int cb_ = (qq) * 64;                                            \
            _Pragma("unroll")                                                     \
            for (int i = 0; i < 8; ++i) {                                         \
                int i0 = cind[cb_ + kg * 8 + i];                                  \
                int i1 = cind[cb_ + 32 + kg * 8 + i];                             \
                if (BF16X) {                                                      \
                    (arr)[i]     = xb[((unsigned)i0 << 6) + chan];                \
                    (arr)[8 + i] = xb[((unsigned)i1 << 6) + chan];                \
                } else {                                                          \
                    (arr)[i]     = f2bf(xf[((unsigned)i0 << 6) + chan]);          \
                    (arr)[8 + i] = f2bf(xf[((unsigned)i1 << 6) + chan]);          \
                }                                                                 \
            }                                                                     \
        }
    #define CONSUME16(qq, arr)                                                    \
        {                                                                         \
            union { uint4 u; bf16x8 b; } b0_, b1_;                                \
            b0_.u = make_uint4(pk2((arr)[0], (arr)[1]),  pk2((arr)[2], (arr)[3]), \
                               pk2((arr)[4], (arr)[5]),  pk2((arr)[6], (arr)[7]));\
            b1_.u = make_uint4(pk2((arr)[8], (arr)[9]),  pk2((arr)[10],(arr)[11]),\
                               pk2((arr)[12],(arr)[13]), pk2((arr)[14],(arr)[15]));\
            bf16x8 a0_ = *(const bf16x8*)&wT[arow * SWT + (qq) * 64 + kg * 8];    \
            bf16x8 a1_ = *(const bf16x8*)&wT[arow * SWT + (qq) * 64 + 32 + kg * 8];\
            f32x4 acc_ = {0.f, 0.f, 0.f, 0.f};                                    \
            acc_ = __builtin_amdgcn_mfma_f32_16x16x32_bf16(a0_, b0_.b, acc_, 0,0,0);\
            acc_ = __builtin_amdgcn_mfma_f32_16x16x32_bf16(a1_, b1_.b, acc_, 0,0,0);\
            STORE_D(qq, acc_)                                                     \
        }
    #define PIPE(LOADM, CONSM)                                                    \
        {                                                                         \
            LOADM(qb0 + 0, va);                                                   \
            _Pragma("unroll")                                                     \
            for (int iq = 0; iq < 8; iq += 2) {                                   \
                LOADM(qb0 + iq + 1, vbuf);                                        \
                CONSM(qb0 + iq, va);                                              \
                if (iq + 2 < 8) LOADM(qb0 + iq + 2, va);                          \
                CONSM(qb0 + iq + 1, vbuf);                                        \
            }                                                                     \
        }
    #define LOADQ4(qq, arr) LOADQ_N(qq, arr, 4)
    #define LOADQ8(qq, arr) LOADQ_N(qq, arr, 8)

    {
        const int qb0 = qh * 8;
        int nmax = 0;
        #pragma unroll
        for (int j = 0; j < 8; ++j) nmax = max(nmax, qcnt[qb0 + j]);   // uniform
        if (nmax <= 16)      { PIPE(LOADQ4,  CONSUME4)  }
        else if (nmax <= 32) { PIPE(LOADQ8,  CONSUME8)  }
        else                 { PIPE(LOADQ16, CONSUME16) }
    }
    __syncthreads();

    // ---------------- Phase C: out[q][o] via MFMA, 6-deep wb prefetch (R12) ----
    {
        const int ot = wid;
        f32x4 c0 = {0.f, 0.f, 0.f, 0.f};
        const ushort_t* wfrow = &WF16[l15 * SWF + kg * 8];
        const ushort_t* bbase = wb + ((size_t)(ot * 64 + lane)) * 8;

        bf16x8 rb0[6];
        #pragma unroll
        for (int i = 0; i < 6; ++i)          // preload jt = 0..5
            rb0[i] = *(const bf16x8*)&bbase[(size_t)i * 4096];
        for (int m = 0; m < 5; ++m) {        // 5 x 6 = 30 jt steps
            #pragma unroll
            for (int u = 0; u < 6; ++u) {
                int jt = m * 6 + u;
                bf16x8 a = *(const bf16x8*)&wfrow[jt * 32];
                c0 = __builtin_amdgcn_mfma_f32_16x16x32_bf16(a, rb0[u], c0, 0, 0, 0);
                if (m < 4)                   // prefetch jt+6 into freed slot
                    rb0[u] = *(const bf16x8*)&bbase[(size_t)(jt + 6) * 4096];
            }
        }

        // C/D layout: col = lane&15, row = (lane>>4)*4 + reg. Rows 0..15 = queries.
        int col = ot * 16 + l15;
        #pragma unroll
        for (int reg = 0; reg < 4; ++reg) {
            int row = kg * 4 + reg;
            float inv = 1.0f / (float)max(cnt[row], 1);
            int gq = q0 + row;
            if (gq < N)
                out[(size_t)gq * COUT + col] = c0[reg] * inv;
        }
    }
}

extern "C" void kernel_launch(void* const* d_in, const int* in_sizes, int n_in,
                              void* d_out, int out_size, void* d_ws, size_t ws_size,
                              hipStream_t stream) {
    const float* q_pts  = (const float*)d_in[0];
    const float* s_pts  = (const float*)d_in[1];
    const int*   nbinds = (const int*)d_in[2];
    const float* x      = (const float*)d_in[3];
    const float* kp     = (const float*)d_in[4];
    const float* wmat   = (const float*)d_in[5];
    float* out = (float*)d_out;
    int N = in_sizes[0] / 3;
    int M = in_sizes[1] / 3;

    // workspace carve: rowsum (M f32) | wb (245760 B) | xb (M*64 bf16)
    size_t    off_wb = ((size_t)M * 4 + 255) & ~(size_t)255;
    size_t    off_xb = (off_wb + 245760 + 255) & ~(size_t)255;
    size_t    need   = off_xb + (size_t)M * CIN * 2;
    float*    rowsum = (float*)d_ws;
    ushort_t* wb     = (ushort_t*)((char*)d_ws + off_wb);
    ushort_t* xb     = (ushort_t*)((char*)d_ws + off_xb);
    bool use_bf16x = (ws_size >= need) && (M < 65536);   // cind is ushort

    prep_kernel<<<(M + 3) / 4, 256, 0, stream>>>(x, rowsum, xb, M, use_bf16x ? 1 : 0);
    wprep_kernel<<<60, 256, 0, stream>>>(wmat, wb);
    int mb = (N + QB - 1) / QB;
    if (use_bf16x)
        kpconv_main<true><<<mb, NT, 0, stream>>>(q_pts, s_pts, nbinds, x, xb, kp,
                                                 wb, rowsum, out, N, M);
    else
        kpconv_main<false><<<mb, NT, 0, stream>>>(q_pts, s_pts, nbinds, x, xb, kp,
                                                  wb, rowsum, out, N, M);
}

// Round 14
// 105.832 us; speedup vs baseline: 1.1865x; 1.0097x over previous
//
#include <hip/hip_runtime.h>
#include <math.h>

// KPConv fused, round 14: R13 + 4-deep Phase-B gather pipeline (latency cover).
// All math / layouts / tiers byte-identical to R13 (passed, 107us).
// Shapes: N=50000, M=50000, H=40, K=15, CIN=64, COUT=128.
typedef unsigned short ushort_t;
typedef __attribute__((ext_vector_type(4))) short bf16x4;   // 4 bf16 = 2 VGPRs
typedef __attribute__((ext_vector_type(8))) short bf16x8;   // 8 bf16 = 4 VGPRs
typedef __attribute__((ext_vector_type(4))) float f32x4;

constexpr int H    = 40;
constexpr int KKP  = 15;
constexpr int CIN  = 64;
constexpr int COUT = 128;
constexpr int QB   = 16;         // queries per block
constexpr int NT   = 512;        // threads per block (8 waves)
constexpr int NP   = QB * H;     // 640 (q,h) pairs per block
constexpr int SWF  = 968;        // WF16 row stride: 1936 B, bank step 4 -> 2-way free
constexpr int SWT  = 1032;       // wT row stride: 2064 B, bank step 4
constexpr float INV_KPE = 1.0f / 1.2f;

#if __has_builtin(__builtin_amdgcn_mfma_f32_16x16x16_bf16)
#define MFMA_K16(a,b,c) __builtin_amdgcn_mfma_f32_16x16x16_bf16(a,b,c,0,0,0)
#else
#define MFMA_K16(a,b,c) __builtin_amdgcn_mfma_f32_16x16x16bf16_1k(a,b,c,0,0,0)
#endif

__device__ __forceinline__ ushort_t f2bf(float f) {   // fp32 -> bf16 RNE
    union { float f; unsigned u; } v; v.f = f;
    unsigned r = v.u + 0x7FFFu + ((v.u >> 16) & 1u);
    return (ushort_t)(r >> 16);
}
__device__ __forceinline__ unsigned pk2(ushort_t a, ushort_t b) {
    return (unsigned)a | ((unsigned)b << 16);
}

// ---- kernel 1: per-support-row feature sums (reduction order UNCHANGED) + bf16 x copy
__global__ __launch_bounds__(256) void prep_kernel(const float* __restrict__ x,
                                                   float* __restrict__ rowsum,
                                                   ushort_t* __restrict__ xb,
                                                   int M, int write_xb) {
    int row  = blockIdx.x * 4 + (threadIdx.x >> 6);
    int lane = threadIdx.x & 63;
    if (row >= M) return;
    float v = x[row * CIN + lane];   // CIN == 64 == wave width
    if (write_xb) xb[row * CIN + lane] = f2bf(v);
    #pragma unroll
    for (int off = 32; off > 0; off >>= 1) v += __shfl_down(v, off, 64);
    if (lane == 0) rowsum[row] = v;
}

// ---- kernel 2: W -> bf16 MFMA-fragment order (UNCHANGED, validated R2..R13) ---
__global__ __launch_bounds__(256) void wprep_kernel(const float* __restrict__ wmat,
                                                    ushort_t* __restrict__ wb) {
    int t = blockIdx.x * 256 + threadIdx.x;
    if (t >= 30 * 8 * 64) return;
    int lane = t & 63;
    int ot   = (t >> 6) & 7;
    int jt   = t >> 9;
    int o  = ot * 16 + (lane & 15);
    int kb = jt * 32 + (lane >> 4) * 8;
    unsigned pk[4];
    #pragma unroll
    for (int r = 0; r < 4; ++r) {
        unsigned lo = f2bf(wmat[(kb + 2 * r) * COUT + o]);
        unsigned hi = f2bf(wmat[(kb + 2 * r + 1) * COUT + o]);
        pk[r] = lo | (hi << 16);
    }
    *(uint4*)&wb[(size_t)t * 8] = make_uint4(pk[0], pk[1], pk[2], pk[3]);
}

// ---- kernel 3: fused KPConv ---------------------------------------------------
// LDS: wT 30960 + WF16 30976 + cind 2048 + qcnt 64 + cnt 64 = 64112 B -> 2 blk/CU
template<bool BF16X>
__global__ __launch_bounds__(NT, 4) void kpconv_main(
    const float* __restrict__ q_pts, const float* __restrict__ s_pts,
    const int*   __restrict__ nbinds, const float* __restrict__ xf,
    const ushort_t* __restrict__ xb,  const float* __restrict__ kp,
    const ushort_t* __restrict__ wb,  const float* __restrict__ rowsum,
    float* __restrict__ out, int N, int M)
{
    __shared__ __align__(16) ushort_t wT[15 * SWT];   // w^T: [kp][q*64+slot] bf16
    __shared__ __align__(16) ushort_t WF16[QB * SWF]; // bf16 WF, [q][k*64+c]
    __shared__ __align__(16) ushort_t cind[QB * 64];  // [q][slot] -> support row
    __shared__ int qcnt[QB];                          // active slots per q
    __shared__ int cnt[QB];                           // valid-neighbor count

    const int tid = threadIdx.x;
    const int q0  = blockIdx.x * QB;

    // zero wT (pad slots must be 0) and cind (pad slots -> row 0, finite x)
    for (int i = tid; i < 15 * SWT / 8; i += NT)      // 1935 uint4
        ((uint4*)wT)[i] = make_uint4(0, 0, 0, 0);
    if (tid < QB * 64 / 8) ((uint4*)cind)[tid] = make_uint4(0, 0, 0, 0);
    if (tid < QB) { qcnt[tid] = 0; cnt[tid] = 0; }
    __syncthreads();

    // ---------------- Phase A: KP weights + validity + compaction --------------
    // (math byte-identical to R8..R13)
    for (int p = tid; p < NP; p += NT) {
        int q  = p / H;
        int h  = p - q * H;
        int gq = q0 + q;
        int ind = nbinds[gq * H + h];
        bool shadow = (ind >= M);
        float nx = 0.f, ny = 0.f, nz = 0.f;
        if (!shadow) {
            nx = s_pts[ind * 3 + 0] - q_pts[gq * 3 + 0];
            ny = s_pts[ind * 3 + 1] - q_pts[gq * 3 + 1];
            nz = s_pts[ind * 3 + 2] - q_pts[gq * 3 + 2];
            if (rowsum[ind] > 0.0f) atomicAdd(&cnt[q], 1);
        }
        float n2 = nx * nx + ny * ny + nz * nz;
        float w[KKP];
        float wmax = 0.f;
        #pragma unroll
        for (int k = 0; k < KKP; ++k) {
            float wv = 0.f;
            if (!shadow) {
                float kx = kp[k * 3 + 0], ky = kp[k * 3 + 1], kz = kp[k * 3 + 2];
                float k2 = kx * kx + ky * ky + kz * kz;
                float cross = nx * kx + ny * ky + nz * kz;
                float sq = fmaxf(n2 + k2 - 2.0f * cross, 0.0f);
                wv = fmaxf(1.0f - sqrtf(sq) * INV_KPE, 0.0f);
            }
            w[k] = wv;
            wmax = fmaxf(wmax, wv);
        }
        if (wmax > 0.f) {
            int slot = atomicAdd(&qcnt[q], 1);
            int col  = q * 64 + slot;
            cind[col] = (ushort_t)ind;
            #pragma unroll
            for (int k = 0; k < KKP; ++k)
                wT[k * SWT + col] = f2bf(w[k]);   // transposed store
        }
    }
    __syncthreads();

    // ---------------- Phase B: WF[q] via MFMA, nc-adaptive, 4-deep pipeline ----
    const int wid  = tid >> 6;
    const int lane = tid & 63;
    const int l15  = lane & 15;
    const int kg   = lane >> 4;
    const int cg   = wid & 3;
    const int qh   = wid >> 2;
    const int chan = cg * 16 + l15;
    const int arow = min(l15, 14);

    #define LOADQ_N(qq, arr, NL)                                                  \
        {                                                                         \
            const int cb_ = (qq) * 64;                                            \
            _Pragma("unroll")                                                     \
            for (int i = 0; i < (NL); ++i) {                                      \
                int i0 = cind[cb_ + kg * (NL) + i];                               \
                if (BF16X) (arr)[i] = xb[((unsigned)i0 << 6) + chan];             \
                else       (arr)[i] = f2bf(xf[((unsigned)i0 << 6) + chan]);       \
            }                                                                     \
        }
    #define STORE_D(qq, acc_)                                                     \
        {                                                                         \
            _Pragma("unroll")                                                     \
            for (int reg = 0; reg < 4; ++reg) {                                   \
                int kpr = kg * 4 + reg;                                           \
                if (kpr < KKP)                                                    \
                    WF16[(qq) * SWF + kpr * 64 + chan] = f2bf(acc_[reg]);         \
            }                                                                     \
        }
    #define CONSUME4(qq, arr)                                                     \
        {                                                                         \
            union { uint2 u; bf16x4 b; } b_;                                      \
            b_.u = make_uint2(pk2((arr)[0], (arr)[1]), pk2((arr)[2], (arr)[3]));  \
            bf16x4 a_ = *(const bf16x4*)&wT[arow * SWT + (qq) * 64 + kg * 4];     \
            f32x4 acc_ = {0.f, 0.f, 0.f, 0.f};                                    \
            acc_ = MFMA_K16(a_, b_.b, acc_);                                      \
            STORE_D(qq, acc_)                                                     \
        }
    #define CONSUME8(qq, arr)                                                     \
        {                                                                         \
            union { uint4 u; bf16x8 b; } b_;                                      \
            b_.u = make_uint4(pk2((arr)[0], (arr)[1]), pk2((arr)[2], (arr)[3]),   \
                              pk2((arr)[4], (arr)[5]), pk2((arr)[6], (arr)[7]));  \
            bf16x8 a_ = *(const bf16x8*)&wT[arow * SWT + (qq) * 64 + kg * 8];     \
            f32x4 acc_ = {0.f, 0.f, 0.f, 0.f};                                    \
            acc_ = __builtin_amdgcn_mfma_f32_16x16x32_bf16(a_, b_.b, acc_, 0,0,0);\
            STORE_D(qq, acc_)                                                     \
        }
    #define LOADQ16(qq, arr)                                                      \
        {                                                                         \
            const int cb_ = (qq) * 64;                                            \
            _Pragma("unroll")                                                     \
            for (int i = 0; i < 8; ++i) {                                         \
                int i0 = cind[cb_ + kg * 8 + i];                                  \
                int i1 = cind[cb_ + 32 + kg * 8 + i];                             \
                if (BF16X) {                                                      \
                    (arr)[i]     = xb[((unsigned)i0 << 6) + chan];                \
                    (arr)[8 + i] = xb[((unsigned)i1 << 6) + chan];                \
                } else {                                                          \
                    (arr)[i]     = f2bf(xf[((unsigned)i0 << 6) + chan]);          \
                    (arr)[8 + i] = f2bf(xf[((unsigned)i1 << 6) + chan]);          \
                }                                                                 \
            }                                                                     \
        }
    #define CONSUME16(qq, arr)                                                    \
        {                                                                         \
            union { uint4 u; bf16x8 b; } b0_, b1_;                                \
            b0_.u = make_uint4(pk2((arr)[0], (arr)[1]),  pk2((arr)[2], (arr)[3]), \
                               pk2((arr)[4], (arr)[5]),  pk2((arr)[6], (arr)[7]));\
            b1_.u = make_uint4(pk2((arr)[8], (arr)[9]),  pk2((arr)[10],(arr)[11]),\
                               pk2((arr)[12],(arr)[13]), pk2((arr)[14],(arr)[15]));\
            bf16x8 a0_ = *(const bf16x8*)&wT[arow * SWT + (qq) * 64 + kg * 8];    \
            bf16x8 a1_ = *(const bf16x8*)&wT[arow * SWT + (qq) * 64 + 32 + kg * 8];\
            f32x4 acc_ = {0.f, 0.f, 0.f, 0.f};                                    \
            acc_ = __builtin_amdgcn_mfma_f32_16x16x32_bf16(a0_, b0_.b, acc_, 0,0,0);\
            acc_ = __builtin_amdgcn_mfma_f32_16x16x32_bf16(a1_, b1_.b, acc_, 0,0,0);\
            STORE_D(qq, acc_)                                                     \
        }
    // 4-deep pipeline: buffers indexed iq&3 inside a fully-unrolled loop
    // (compile-time indices -> registers, not scratch).
    #define PIPE4(LOADM, CONSM, NE)                                               \
        {                                                                         \
            ushort_t bufs[4][NE];                                                 \
            LOADM(qb0 + 0, bufs[0]);                                              \
            LOADM(qb0 + 1, bufs[1]);                                              \
            LOADM(qb0 + 2, bufs[2]);                                              \
            LOADM(qb0 + 3, bufs[3]);                                              \
            _Pragma("unroll")                                                     \
            for (int iq = 0; iq < 8; ++iq) {                                      \
                CONSM(qb0 + iq, bufs[iq & 3]);                                    \
                if (iq + 4 < 8) LOADM(qb0 + iq + 4, bufs[iq & 3]);                \
            }                                                                     \
        }
    #define PIPE2_16()                                                            \
        {                                                                         \
            ushort_t va[16], vbuf[16];                                            \
            LOADQ16(qb0 + 0, va);                                                 \
            _Pragma("unroll")                                                     \
            for (int iq = 0; iq < 8; iq += 2) {                                   \
                LOADQ16(qb0 + iq + 1, vbuf);                                      \
                CONSUME16(qb0 + iq, va);                                          \
                if (iq + 2 < 8) LOADQ16(qb0 + iq + 2, va);                        \
                CONSUME16(qb0 + iq + 1, vbuf);                                    \
            }                                                                     \
        }
    #define LOADQ4(qq, arr) LOADQ_N(qq, arr, 4)
    #define LOADQ8(qq, arr) LOADQ_N(qq, arr, 8)

    {
        const int qb0 = qh * 8;
        int nmax = 0;
        #pragma unroll
        for (int j = 0; j < 8; ++j) nmax = max(nmax, qcnt[qb0 + j]);   // uniform
        if (nmax <= 16)      { PIPE4(LOADQ4, CONSUME4, 4) }
        else if (nmax <= 32) { PIPE4(LOADQ8, CONSUME8, 8) }
        else                 { PIPE2_16() }
    }
    __syncthreads();

    // ---------------- Phase C: out[q][o] via MFMA, 6-deep wb prefetch (R12) ----
    {
        const int ot = wid;
        f32x4 c0 = {0.f, 0.f, 0.f, 0.f};
        const ushort_t* wfrow = &WF16[l15 * SWF + kg * 8];
        const ushort_t* bbase = wb + ((size_t)(ot * 64 + lane)) * 8;

        bf16x8 rb0[6];
        #pragma unroll
        for (int i = 0; i < 6; ++i)          // preload jt = 0..5
            rb0[i] = *(const bf16x8*)&bbase[(size_t)i * 4096];
        for (int m = 0; m < 5; ++m) {        // 5 x 6 = 30 jt steps
            #pragma unroll
            for (int u = 0; u < 6; ++u) {
                int jt = m * 6 + u;
                bf16x8 a = *(const bf16x8*)&wfrow[jt * 32];
                c0 = __builtin_amdgcn_mfma_f32_16x16x32_bf16(a, rb0[u], c0, 0, 0, 0);
                if (m < 4)                   // prefetch jt+6 into freed slot
                    rb0[u] = *(const bf16x8*)&bbase[(size_t)(jt + 6) * 4096];
            }
        }

        // C/D layout: col = lane&15, row = (lane>>4)*4 + reg. Rows 0..15 = queries.
        int col = ot * 16 + l15;
        #pragma unroll
        for (int reg = 0; reg < 4; ++reg) {
            int row = kg * 4 + reg;
            float inv = 1.0f / (float)max(cnt[row], 1);
            int gq = q0 + row;
            if (gq < N)
                out[(size_t)gq * COUT + col] = c0[reg] * inv;
        }
    }
}

extern "C" void kernel_launch(void* const* d_in, const int* in_sizes, int n_in,
                              void* d_out, int out_size, void* d_ws, size_t ws_size,
                              hipStream_t stream) {
    const float* q_pts  = (const float*)d_in[0];
    const float* s_pts  = (const float*)d_in[1];
    const int*   nbinds = (const int*)d_in[2];
    const float* x      = (const float*)d_in[3];
    const float* kp     = (const float*)d_in[4];
    const float* wmat   = (const float*)d_in[5];
    float* out = (float*)d_out;
    int N = in_sizes[0] / 3;
    int M = in_sizes[1] / 3;

    // workspace carve: rowsum (M f32) | wb (245760 B) | xb (M*64 bf16)
    size_t    off_wb = ((size_t)M * 4 + 255) & ~(size_t)255;
    size_t    off_xb = (off_wb + 245760 + 255) & ~(size_t)255;
    size_t    need   = off_xb + (size_t)M * CIN * 2;
    float*    rowsum = (float*)d_ws;
    ushort_t* wb     = (ushort_t*)((char*)d_ws + off_wb);
    ushort_t* xb     = (ushort_t*)((char*)d_ws + off_xb);
    bool use_bf16x = (ws_size >= need) && (M < 65536);   // cind is ushort

    prep_kernel<<<(M + 3) / 4, 256, 0, stream>>>(x, rowsum, xb, M, use_bf16x ? 1 : 0);
    wprep_kernel<<<60, 256, 0, stream>>>(wmat, wb);
    int mb = (N + QB - 1) / QB;
    if (use_bf16x)
        kpconv_main<true><<<mb, NT, 0, stream>>>(q_pts, s_pts, nbinds, x, xb, kp,
                                                 wb, rowsum, out, N, M);
    else
        kpconv_main<false><<<mb, NT, 0, stream>>>(q_pts, s_pts, nbinds, x, xb, kp,
                                                  wb, rowsum, out, N, M);
}